// Round 9
// baseline (261.065 us; speedup 1.0000x reference)
//
#include <hip/hip_runtime.h>
#include <hip/hip_bf16.h>

using short8  = __attribute__((ext_vector_type(8))) short;
using short4v = __attribute__((ext_vector_type(4))) short;
using f32x4   = __attribute__((ext_vector_type(4))) float;

#if __has_builtin(__builtin_amdgcn_exp2f)
#define EXP2(x) __builtin_amdgcn_exp2f(x)
#else
#define EXP2(x) __expf(0.6931471805599453f*(x))
#endif

__device__ __forceinline__ unsigned short f2bf(float x){
  union { float f; unsigned u; } c; c.f = x;
  unsigned u = c.u + 0x7FFFu + ((c.u >> 16) & 1u);
  return (unsigned short)(u >> 16);
}

__device__ __forceinline__ unsigned pack_bf16_rn(float a, float b){
  __hip_bfloat162 t = __float22bfloat162_rn(make_float2(a, b));
  unsigned u; __builtin_memcpy(&u, &t, 4);
  return u;
}

// ---------------- fused prep: dtype conversions + mask bit-pack (transposed) ----
// bid < 8192: bf16 conversions (X, Wq*log2e/8, Wk, Wv, Wo)
// bid in [8192,12288): mask -> 1 bit/key via ballot, TRANSPOSED layout:
// Mbits[word][row], word w covers keys w*64..w*64+63 of row (b*2048+q).
__global__ __launch_bounds__(256) void prep(const float* __restrict__ X, const int* __restrict__ Mk,
                                            const float* __restrict__ Wq, const float* __restrict__ Wk,
                                            const float* __restrict__ Wv, const float* __restrict__ Wo,
                                            unsigned short* __restrict__ Xb, unsigned short* __restrict__ Wqkv,
                                            unsigned short* __restrict__ Wob, unsigned long long* __restrict__ Mbits)
{
  const int bid = blockIdx.x, tid = threadIdx.x;
  if (bid < 8192){
    const float* src; unsigned short* dst; float scale; int i;
    if (bid < 4096)      { src = X;  dst = Xb;             scale = 1.0f;          i = bid*1024 + tid*4; }
    else if (bid < 5120) { src = Wq; dst = Wqkv;           scale = 0.18033688f;   i = (bid-4096)*1024 + tid*4; } // 1/8 * log2(e)
    else if (bid < 6144) { src = Wk; dst = Wqkv + 1048576; scale = 1.0f;          i = (bid-5120)*1024 + tid*4; }
    else if (bid < 7168) { src = Wv; dst = Wqkv + 2097152; scale = 1.0f;          i = (bid-6144)*1024 + tid*4; }
    else                 { src = Wo; dst = Wob;            scale = 1.0f;          i = (bid-7168)*1024 + tid*4; }
    float4 v = *(const float4*)(src + i);
    ushort4 o;
    o.x = f2bf(v.x * scale); o.y = f2bf(v.y * scale);
    o.z = f2bf(v.z * scale); o.w = f2bf(v.w * scale);
    *(ushort4*)(dst + i) = o;
  } else {
    int row = bid - 8192;                       // 0..4095 = b*2048+q
    const int* src = Mk + (size_t)row * 2048;
    int w = tid >> 6, l = tid & 63;
    #pragma unroll
    for (int p = 0; p < 8; p++){
      int v = src[w*512 + p*64 + l];            // coalesced 256B per ballot
      unsigned long long bm = __ballot(v != 0);
      if (l == 0) Mbits[(size_t)(w*8 + p) * 4096 + row] = bm;  // [word][row]
    }
  }
}

// ---------------- async global->LDS, width 16 ----------------
__device__ __forceinline__ void stage16(const unsigned short* g, unsigned short* l){
  __builtin_amdgcn_global_load_lds(
      (const __attribute__((address_space(1))) void*)g,
      (__attribute__((address_space(3))) void*)l, 16, 0, 0);
}

// ---------------- gemm1: QKV = Xb * Wqkv^T; V-blocks write Vg transposed ----------
__global__ __launch_bounds__(256) void gemm_qkv(const unsigned short* __restrict__ A,
                                                const unsigned short* __restrict__ B,
                                                unsigned short* __restrict__ C,
                                                unsigned short* __restrict__ Vg)
{
  __shared__ unsigned short As[128*32];
  __shared__ unsigned short Bs[128*32];
  const int tid = threadIdx.x;
  const int wave = tid >> 6, lane = tid & 63, l16 = lane & 15, quad = lane >> 4;
  const int id = blockIdx.x, xcd = id & 7, m = id >> 3;
  const int bm = (m / 3) * 128, bn = (xcd * 3 + (m % 3)) * 128;
  const int wm = (wave >> 1) * 64, wn = (wave & 1) * 64;
  const int K = 1024;

  f32x4 acc[4][4] = {};
  for (int k0 = 0; k0 < K; k0 += 32){
    #pragma unroll
    for (int c = 0; c < 2; c++){
      int idx = c * 256 + tid;
      int row = idx >> 2, g = (idx & 3) * 8;
      stage16(A + (size_t)(bm + row) * K + k0 + g, &As[idx * 8]);
      stage16(B + (size_t)(bn + row) * K + k0 + g, &Bs[idx * 8]);
    }
    __syncthreads();
    short8 af[4], bf[4];
    #pragma unroll
    for (int i = 0; i < 4; i++) af[i] = *(const short8*)&As[(wm + i*16 + l16)*32 + quad*8];
    #pragma unroll
    for (int j = 0; j < 4; j++) bf[j] = *(const short8*)&Bs[(wn + j*16 + l16)*32 + quad*8];
    #pragma unroll
    for (int i = 0; i < 4; i++)
      #pragma unroll
      for (int j = 0; j < 4; j++)
        acc[i][j] = __builtin_amdgcn_mfma_f32_16x16x32_bf16(af[i], bf[j], acc[i][j], 0, 0, 0);
    __syncthreads();
  }

  if (bn < 2048){
    #pragma unroll
    for (int i = 0; i < 4; i++){
      int mrow = bm + wm + i*16 + quad*4;
      #pragma unroll
      for (int j = 0; j < 4; j++){
        int ncol = bn + wn + j*16 + l16;
        #pragma unroll
        for (int r = 0; r < 4; r++)
          C[(size_t)(mrow + r) * 3072 + ncol] = f2bf(acc[i][j][r]);
      }
    }
  } else {
    #pragma unroll
    for (int i = 0; i < 4; i++){
      int srow = bm + wm + i*16 + quad*4;
      int b = srow >> 11, s = srow & 2047;
      #pragma unroll
      for (int j = 0; j < 4; j++){
        int c = bn - 2048 + wn + j*16 + l16;
        int h = c >> 6, d = c & 63;
        ushort4 o;
        o.x = f2bf(acc[i][j][0]); o.y = f2bf(acc[i][j][1]);
        o.z = f2bf(acc[i][j][2]); o.w = f2bf(acc[i][j][3]);
        *(ushort4*)&Vg[((size_t)(b*16 + h)*64 + d) * 2048 + s] = o;
      }
    }
  }
}

// ---------------- gemm2: out = Ob * Wob^T (f32 out), 128x64 tiles, XCD-swizzled ----
__global__ __launch_bounds__(256) void gemm_out(const unsigned short* __restrict__ A,
                                                const unsigned short* __restrict__ B,
                                                float* __restrict__ Cf)
{
  __shared__ unsigned short As[128*32];
  __shared__ unsigned short Bs[64*32];
  const int tid = threadIdx.x;
  const int wave = tid >> 6, lane = tid & 63, l16 = lane & 15, quad = lane >> 4;
  const int id = blockIdx.x, xcd = id & 7, m = id >> 3;
  const int bm = (m >> 1) * 128, bn = (xcd * 2 + (m & 1)) * 64;
  const int wm = (wave >> 1) * 64, wn = (wave & 1) * 32;
  const int K = 1024, N = 1024;

  f32x4 acc[4][2] = {};
  for (int k0 = 0; k0 < K; k0 += 32){
    #pragma unroll
    for (int c = 0; c < 2; c++){
      int idx = c * 256 + tid;
      int row = idx >> 2, g = (idx & 3) * 8;
      stage16(A + (size_t)(bm + row) * K + k0 + g, &As[idx * 8]);
    }
    stage16(B + (size_t)(bn + (tid >> 2)) * K + k0 + (tid & 3) * 8, &Bs[tid * 8]);
    __syncthreads();
    short8 af[4], bf[2];
    #pragma unroll
    for (int i = 0; i < 4; i++) af[i] = *(const short8*)&As[(wm + i*16 + l16)*32 + quad*8];
    #pragma unroll
    for (int j = 0; j < 2; j++) bf[j] = *(const short8*)&Bs[(wn + j*16 + l16)*32 + quad*8];
    #pragma unroll
    for (int i = 0; i < 4; i++)
      #pragma unroll
      for (int j = 0; j < 2; j++)
        acc[i][j] = __builtin_amdgcn_mfma_f32_16x16x32_bf16(af[i], bf[j], acc[i][j], 0, 0, 0);
    __syncthreads();
  }
  #pragma unroll
  for (int i = 0; i < 4; i++){
    int mrow = bm + wm + i*16 + quad*4;
    #pragma unroll
    for (int j = 0; j < 2; j++){
      int ncol = bn + wn + j*16 + l16;
      #pragma unroll
      for (int r = 0; r < 4; r++)
        Cf[(size_t)(mrow + r) * N + ncol] = acc[i][j][r];
    }
  }
}

// ---------------- attention: wave-autonomous + counted-vmcnt 3-slot ring --------
// Round 7 (wave-autonomous, P in regs) got 101->74.6us. Remaining stall: the per-
// chunk __syncthreads carried vmcnt(0) -- every wave drained the JUST-issued
// prefetch DMAs each iteration (T3/T4: never drain vmcnt to 0 in the main loop).
// Now: 3-slot K/V ring staging 2 chunks ahead; per-iter wait uses a COUNTED
// vmcnt. Robust accounting: each iteration issues exactly 5 VMEM ops (4
// global_load_lds + 1 mask load) bounded by the asm memory clobbers, so the
// youngest 5 outstanding at iteration c's wait are exactly iteration c-1's ops
// IN ANY INTERNAL ORDER -> vmcnt(5) retires everything through iteration c-2,
// i.e. chunk c's DMAs + its mask. (vmcnt(6) was only safe if the compiler kept
// the mask load after the DMAs -- not guaranteed.) c==0 drains the 10-op
// prologue with vmcnt(0); c==31 drains the last chunk with vmcnt(0).
// setprio removed from the dense loop (m190). LDS 48KB -> 3 blocks/CU
// (rounds 2-4: residency is not the wall).
__global__ __launch_bounds__(256, 3) void attn(const unsigned short* __restrict__ QKV,
                                               const unsigned short* __restrict__ Vg,
                                               const unsigned long long* __restrict__ Mb,
                                               unsigned short* __restrict__ O)
{
  __shared__ char smem[49152];
  unsigned short* Ks = (unsigned short*)smem;            // [3][64][64] xor-swizzled 16B blocks
  unsigned short* Vt = (unsigned short*)(smem + 24576);  // [3][64][64] [d][key] xor-swizzled

  const int tid = threadIdx.x, wave = tid >> 6, lane = tid & 63;
  const int l16 = lane & 15, quad = lane >> 4;
  const int id = blockIdx.x;
  const int xcd = id & 7, m = id >> 3;         // round-robin XCD assumption
  const int bh = xcd * 4 + (m >> 5);           // 4 bh per XCD (K/V stay in this XCD's L2)
  const int qblk = (m & 31) * 64;
  const int b = bh >> 4, h = bh & 15;
  const unsigned short* Qg  = QKV + (size_t)b * 2048 * 3072 + h * 64;
  const unsigned short* Kg  = Qg + 1024;
  const unsigned short* Vgb = Vg + (size_t)bh * 64 * 2048;

  const int qrow = qblk + wave*16 + l16;       // this lane's q (B-frag row, lsum owner)
  const unsigned long long* mrow = Mb + (size_t)b*2048 + qrow;   // + c*4096 per chunk

  // Q B-fragment: B[n=q=l16][k=d=ks*32+quad*8+j]
  short8 qf0 = *(const short8*)(Qg + (size_t)qrow * 3072 + quad*8);
  short8 qf1 = *(const short8*)(Qg + (size_t)qrow * 3072 + 32 + quad*8);

  f32x4 oacc[4] = {};               // O[q=quad*4+r][d=ng*16+l16]
  float plsum = 0.f;
  const int sw = l16 & 7;

  // per-thread staging geometry (row, swizzled block) -- constant across chunks
  const int s0 = tid, s1 = 256 + tid;
  const int row0 = s0 >> 3, bg0 = (s0 & 7) ^ (row0 & 7);
  const int row1 = s1 >> 3, bg1 = (s1 & 7) ^ (row1 & 7);

  // prologue: stage chunks 0,1 into slots 0,1; prefetch masks 0,1 (10 VMEM ops)
  stage16(Kg  + (size_t)row0 * 3072 + bg0 * 8,      Ks + s0 * 8);
  stage16(Vgb + (size_t)row0 * 2048 + bg0 * 8,      Vt + s0 * 8);
  stage16(Kg  + (size_t)row1 * 3072 + bg1 * 8,      Ks + s1 * 8);
  stage16(Vgb + (size_t)row1 * 2048 + bg1 * 8,      Vt + s1 * 8);
  stage16(Kg  + (size_t)(64 + row0) * 3072 + bg0 * 8, Ks + 4096 + s0 * 8);
  stage16(Vgb + (size_t)row0 * 2048 + 64 + bg0 * 8,   Vt + 4096 + s0 * 8);
  stage16(Kg  + (size_t)(64 + row1) * 3072 + bg1 * 8, Ks + 4096 + s1 * 8);
  stage16(Vgb + (size_t)row1 * 2048 + 64 + bg1 * 8,   Vt + 4096 + s1 * 8);
  unsigned long long mcur = mrow[0];
  unsigned long long mnxt = mrow[4096];
  unsigned long long mnn  = 0ull;

  int sc = 0;                        // slot of chunk c
  for (int c = 0; c < 32; c++){
    // wait: chunk-c DMAs landed (counted, order-robust); my LDS reads of the
    // ring slot being re-targeted are done (lgkm)
    if (c == 0 || c == 31){
      __asm__ volatile("s_waitcnt vmcnt(0) lgkmcnt(0)" ::: "memory");
    } else {
      __asm__ volatile("s_waitcnt vmcnt(5) lgkmcnt(0)" ::: "memory");
    }
    __builtin_amdgcn_s_barrier();
    __builtin_amdgcn_sched_barrier(0);

    // issue chunk c+2 DMAs into slot (sc+2)%3 + mask prefetch (5 VMEM ops)
    if (c < 30){
      int s2 = sc + 2; if (s2 >= 3) s2 -= 3;
      const int nj = (c + 2) * 64;
      const int kb2 = s2 * 4096;
      stage16(Kg  + (size_t)(nj + row0) * 3072 + bg0 * 8, Ks + kb2 + s0 * 8);
      stage16(Vgb + (size_t)row0 * 2048 + nj + bg0 * 8,   Vt + kb2 + s0 * 8);
      stage16(Kg  + (size_t)(nj + row1) * 3072 + bg1 * 8, Ks + kb2 + s1 * 8);
      stage16(Vgb + (size_t)row1 * 2048 + nj + bg1 * 8,   Vt + kb2 + s1 * 8);
      mnn = mrow[(size_t)(c + 2) * 4096];
    }

    // fully wave-private body on slot sc: 4 key-blocks; QK -> exp -> in-reg P -> PV
    const int buf = sc * 4096;
    #pragma unroll
    for (int kb = 0; kb < 4; kb++){
      const int krow = kb*16 + l16;           // A[m=key] row in Ks
      short8 kf0 = *(const short8*)&Ks[buf + krow*64 + ((0 + quad) ^ sw) * 8];
      short8 kf1 = *(const short8*)&Ks[buf + krow*64 + ((4 + quad) ^ sw) * 8];
      f32x4 a = {0.f, 0.f, 0.f, 0.f};
      a = __builtin_amdgcn_mfma_f32_16x16x32_bf16(kf0, qf0, a, 0, 0, 0);
      a = __builtin_amdgcn_mfma_f32_16x16x32_bf16(kf1, qf1, a, 0, 0, 0);
      // S^T[key=quad*4+r][q=l16]; log2 domain (log2e folded into Wq); masked -> 1.0
      unsigned mm = (unsigned)(mcur >> (kb*16 + quad*4)) & 15u;
      float p0 = EXP2(a[0]); p0 = (mm & 1u) ? p0 : 1.0f;
      float p1 = EXP2(a[1]); p1 = (mm & 2u) ? p1 : 1.0f;
      float p2 = EXP2(a[2]); p2 = (mm & 4u) ? p2 : 1.0f;
      float p3 = EXP2(a[3]); p3 = (mm & 8u) ? p3 : 1.0f;
      plsum += (p0 + p1) + (p2 + p3);
      uint2 pu; pu.x = pack_bf16_rn(p0, p1); pu.y = pack_bf16_rn(p2, p3);
      short4v pa = *(short4v*)&pu;            // A[m=q=l16][k=key=quad*4+j] == S^T regs
      #pragma unroll
      for (int ng = 0; ng < 4; ng++){
        const int vrow = ng*16 + l16;         // B[n=d] row in Vt
        short4v vf = *(const short4v*)&Vt[buf + vrow*64 +
                       ((kb*2 + (quad >> 1)) ^ sw) * 8 + (quad & 1) * 4];
        oacc[ng] = __builtin_amdgcn_mfma_f32_16x16x16bf16_1k(pa, vf, oacc[ng], 0, 0, 0);
      }
    }
    mcur = mnxt; mnxt = mnn;
    sc += 1; if (sc == 3) sc = 0;
  }

  // ---- epilogue: shfl-only lsum reduce; scale; direct store (no LDS, no sync) ----
  float v = plsum;
  v += __shfl_xor(v, 16);
  v += __shfl_xor(v, 32);
  float linv = 1.0f / v;                      // total for q = l16
  float lr[4];
  #pragma unroll
  for (int r = 0; r < 4; r++) lr[r] = __shfl(linv, quad*4 + r);   // for q = quad*4+r

  unsigned short* Ob = O + (size_t)(b*2048 + qblk + wave*16) * 1024 + h*64;
  #pragma unroll
  for (int ng = 0; ng < 4; ng++)
    #pragma unroll
    for (int r = 0; r < 4; r++)
      Ob[(size_t)(quad*4 + r) * 1024 + ng*16 + l16] = f2bf(oacc[ng][r] * lr[r]);
}

// ---------------- launch ----------------
extern "C" void kernel_launch(void* const* d_in, const int* in_sizes, int n_in,
                              void* d_out, int out_size, void* d_ws, size_t ws_size,
                              hipStream_t stream)
{
  const float* X  = (const float*)d_in[0];
  const int*   Mk = (const int*)d_in[1];
  const float* Wq = (const float*)d_in[2];
  const float* Wk = (const float*)d_in[3];
  const float* Wv = (const float*)d_in[4];
  const float* Wo = (const float*)d_in[5];
  float* out = (float*)d_out;

  char* ws = (char*)d_ws;
  unsigned short* Xb   = (unsigned short*)(ws + 0);          //  8 MB  [4096][1024]
  unsigned short* Wqkv = (unsigned short*)(ws + 8388608);    //  6 MB  [3072][1024]
  unsigned short* Wob  = (unsigned short*)(ws + 14680064);   //  2 MB  [1024][1024]
  unsigned short* QKV  = (unsigned short*)(ws + 16777216);   // 24 MB  [4096][3072] (V cols unused)
  unsigned short* Ob   = (unsigned short*)(ws + 41943040);   //  8 MB  [4096][1024]
  unsigned long long* Mb = (unsigned long long*)(ws + 50331648); // 1 MB [32 words][4096 rows]
  unsigned short* Vg   = (unsigned short*)(ws + 58720256);   //  8 MB  [32][64][2048]

  prep<<<12288, 256, 0, stream>>>(X, Mk, Wq, Wk, Wv, Wo, Xb, Wqkv, Wob, Mb);
  gemm_qkv<<<768, 256, 0, stream>>>(Xb, Wqkv, QKV, Vg);
  attn<<<1024, 256, 0, stream>>>(QKV, Vg, Mb, Ob);
  gemm_out<<<512, 256, 0, stream>>>(Ob, Wob, out);
}

// Round 10
// 247.388 us; speedup vs baseline: 1.0553x; 1.0553x over previous
//
#include <hip/hip_runtime.h>
#include <hip/hip_bf16.h>

using short8  = __attribute__((ext_vector_type(8))) short;
using short4v = __attribute__((ext_vector_type(4))) short;
using f32x4   = __attribute__((ext_vector_type(4))) float;

#if __has_builtin(__builtin_amdgcn_exp2f)
#define EXP2(x) __builtin_amdgcn_exp2f(x)
#else
#define EXP2(x) __expf(0.6931471805599453f*(x))
#endif

__device__ __forceinline__ unsigned short f2bf(float x){
  union { float f; unsigned u; } c; c.f = x;
  unsigned u = c.u + 0x7FFFu + ((c.u >> 16) & 1u);
  return (unsigned short)(u >> 16);
}

__device__ __forceinline__ unsigned pack_bf16_rn(float a, float b){
  __hip_bfloat162 t = __float22bfloat162_rn(make_float2(a, b));
  unsigned u; __builtin_memcpy(&u, &t, 4);
  return u;
}

// ---------------- fused prep: dtype conversions + mask bit-pack (transposed) ----
// bid < 8192: bf16 conversions (X, Wq*log2e/8, Wk, Wv, Wo)
// bid in [8192,12288): mask -> 1 bit/key via ballot, TRANSPOSED layout:
// Mbits[word][row], word w covers keys w*64..w*64+63 of row (b*2048+q).
__global__ __launch_bounds__(256) void prep(const float* __restrict__ X, const int* __restrict__ Mk,
                                            const float* __restrict__ Wq, const float* __restrict__ Wk,
                                            const float* __restrict__ Wv, const float* __restrict__ Wo,
                                            unsigned short* __restrict__ Xb, unsigned short* __restrict__ Wqkv,
                                            unsigned short* __restrict__ Wob, unsigned long long* __restrict__ Mbits)
{
  const int bid = blockIdx.x, tid = threadIdx.x;
  if (bid < 8192){
    const float* src; unsigned short* dst; float scale; int i;
    if (bid < 4096)      { src = X;  dst = Xb;             scale = 1.0f;          i = bid*1024 + tid*4; }
    else if (bid < 5120) { src = Wq; dst = Wqkv;           scale = 0.18033688f;   i = (bid-4096)*1024 + tid*4; } // 1/8 * log2(e)
    else if (bid < 6144) { src = Wk; dst = Wqkv + 1048576; scale = 1.0f;          i = (bid-5120)*1024 + tid*4; }
    else if (bid < 7168) { src = Wv; dst = Wqkv + 2097152; scale = 1.0f;          i = (bid-6144)*1024 + tid*4; }
    else                 { src = Wo; dst = Wob;            scale = 1.0f;          i = (bid-7168)*1024 + tid*4; }
    float4 v = *(const float4*)(src + i);
    ushort4 o;
    o.x = f2bf(v.x * scale); o.y = f2bf(v.y * scale);
    o.z = f2bf(v.z * scale); o.w = f2bf(v.w * scale);
    *(ushort4*)(dst + i) = o;
  } else {
    int row = bid - 8192;                       // 0..4095 = b*2048+q
    const int* src = Mk + (size_t)row * 2048;
    int w = tid >> 6, l = tid & 63;
    #pragma unroll
    for (int p = 0; p < 8; p++){
      int v = src[w*512 + p*64 + l];            // coalesced 256B per ballot
      unsigned long long bm = __ballot(v != 0);
      if (l == 0) Mbits[(size_t)(w*8 + p) * 4096 + row] = bm;  // [word][row]
    }
  }
}

// ---------------- async global->LDS, width 16 ----------------
__device__ __forceinline__ void stage16(const unsigned short* g, unsigned short* l){
  __builtin_amdgcn_global_load_lds(
      (const __attribute__((address_space(1))) void*)g,
      (__attribute__((address_space(3))) void*)l, 16, 0, 0);
}

// ---------------- gemm1: QKV = Xb * Wqkv^T; V-blocks write Vg transposed ----------
__global__ __launch_bounds__(256) void gemm_qkv(const unsigned short* __restrict__ A,
                                                const unsigned short* __restrict__ B,
                                                unsigned short* __restrict__ C,
                                                unsigned short* __restrict__ Vg)
{
  __shared__ unsigned short As[128*32];
  __shared__ unsigned short Bs[128*32];
  const int tid = threadIdx.x;
  const int wave = tid >> 6, lane = tid & 63, l16 = lane & 15, quad = lane >> 4;
  const int id = blockIdx.x, xcd = id & 7, m = id >> 3;
  const int bm = (m / 3) * 128, bn = (xcd * 3 + (m % 3)) * 128;
  const int wm = (wave >> 1) * 64, wn = (wave & 1) * 64;
  const int K = 1024;

  f32x4 acc[4][4] = {};
  for (int k0 = 0; k0 < K; k0 += 32){
    #pragma unroll
    for (int c = 0; c < 2; c++){
      int idx = c * 256 + tid;
      int row = idx >> 2, g = (idx & 3) * 8;
      stage16(A + (size_t)(bm + row) * K + k0 + g, &As[idx * 8]);
      stage16(B + (size_t)(bn + row) * K + k0 + g, &Bs[idx * 8]);
    }
    __syncthreads();
    short8 af[4], bf[4];
    #pragma unroll
    for (int i = 0; i < 4; i++) af[i] = *(const short8*)&As[(wm + i*16 + l16)*32 + quad*8];
    #pragma unroll
    for (int j = 0; j < 4; j++) bf[j] = *(const short8*)&Bs[(wn + j*16 + l16)*32 + quad*8];
    #pragma unroll
    for (int i = 0; i < 4; i++)
      #pragma unroll
      for (int j = 0; j < 4; j++)
        acc[i][j] = __builtin_amdgcn_mfma_f32_16x16x32_bf16(af[i], bf[j], acc[i][j], 0, 0, 0);
    __syncthreads();
  }

  if (bn < 2048){
    #pragma unroll
    for (int i = 0; i < 4; i++){
      int mrow = bm + wm + i*16 + quad*4;
      #pragma unroll
      for (int j = 0; j < 4; j++){
        int ncol = bn + wn + j*16 + l16;
        #pragma unroll
        for (int r = 0; r < 4; r++)
          C[(size_t)(mrow + r) * 3072 + ncol] = f2bf(acc[i][j][r]);
      }
    }
  } else {
    #pragma unroll
    for (int i = 0; i < 4; i++){
      int srow = bm + wm + i*16 + quad*4;
      int b = srow >> 11, s = srow & 2047;
      #pragma unroll
      for (int j = 0; j < 4; j++){
        int c = bn - 2048 + wn + j*16 + l16;
        int h = c >> 6, d = c & 63;
        ushort4 o;
        o.x = f2bf(acc[i][j][0]); o.y = f2bf(acc[i][j][1]);
        o.z = f2bf(acc[i][j][2]); o.w = f2bf(acc[i][j][3]);
        *(ushort4*)&Vg[((size_t)(b*16 + h)*64 + d) * 2048 + s] = o;
      }
    }
  }
}

// ---------------- gemm2: out = Ob * Wob^T (f32 out), 128x64 tiles, XCD-swizzled ----
__global__ __launch_bounds__(256) void gemm_out(const unsigned short* __restrict__ A,
                                                const unsigned short* __restrict__ B,
                                                float* __restrict__ Cf)
{
  __shared__ unsigned short As[128*32];
  __shared__ unsigned short Bs[64*32];
  const int tid = threadIdx.x;
  const int wave = tid >> 6, lane = tid & 63, l16 = lane & 15, quad = lane >> 4;
  const int id = blockIdx.x, xcd = id & 7, m = id >> 3;
  const int bm = (m >> 1) * 128, bn = (xcd * 2 + (m & 1)) * 64;
  const int wm = (wave >> 1) * 64, wn = (wave & 1) * 32;
  const int K = 1024, N = 1024;

  f32x4 acc[4][2] = {};
  for (int k0 = 0; k0 < K; k0 += 32){
    #pragma unroll
    for (int c = 0; c < 2; c++){
      int idx = c * 256 + tid;
      int row = idx >> 2, g = (idx & 3) * 8;
      stage16(A + (size_t)(bm + row) * K + k0 + g, &As[idx * 8]);
    }
    stage16(B + (size_t)(bn + (tid >> 2)) * K + k0 + (tid & 3) * 8, &Bs[tid * 8]);
    __syncthreads();
    short8 af[4], bf[2];
    #pragma unroll
    for (int i = 0; i < 4; i++) af[i] = *(const short8*)&As[(wm + i*16 + l16)*32 + quad*8];
    #pragma unroll
    for (int j = 0; j < 2; j++) bf[j] = *(const short8*)&Bs[(wn + j*16 + l16)*32 + quad*8];
    #pragma unroll
    for (int i = 0; i < 4; i++)
      #pragma unroll
      for (int j = 0; j < 2; j++)
        acc[i][j] = __builtin_amdgcn_mfma_f32_16x16x32_bf16(af[i], bf[j], acc[i][j], 0, 0, 0);
    __syncthreads();
  }
  #pragma unroll
  for (int i = 0; i < 4; i++){
    int mrow = bm + wm + i*16 + quad*4;
    #pragma unroll
    for (int j = 0; j < 2; j++){
      int ncol = bn + wn + j*16 + l16;
      #pragma unroll
      for (int r = 0; r < 4; r++)
        Cf[(size_t)(mrow + r) * N + ncol] = acc[i][j][r];
    }
  }
}

// ---------------- attention: wave-autonomous, 8-wave blocks, counted-vmcnt ring --
// Round 7 (wave-autonomous, 4-wave blocks, syncthreads): 74.6us, issue-bound
// (VALU 63 + MFMA 29 = 91%). Round 9 (3-slot ring, 48KB, 4-wave blocks): 97us --
// REGRESSION fully explained by occupancy: 48KB -> 3 of 4 blocks resident, all
// counters scaled x0.75, wall x4/3. The wave-autonomous kernel is issue-bound,
// so resident-wave count is now first-order (unlike the old phase-locked one).
// Fix: 8-wave blocks (512 thr), grid 512 = exactly 2 blocks/CU -> 16 waves/CU
// restored AND the 3-slot counted-vmcnt ring kept (2 x 48KB = 96KB). Staging
// amortizes over 8 waves: per-iter VMEM = 2 stage16 + 1 mask = 3 ops, bounded
// by asm memory clobbers -> at iter c, youngest 3 = iter c-1's ops in ANY
// order, so vmcnt(3) retires everything through iter c-2 (chunk c's K+V+mask).
// vmcnt(0) only at c==0 (10-op prologue) and c==31 (tail). Each bh's K/V now
// read by 16 blocks (was 32) -> less L2/HBM re-fetch.
__global__ __launch_bounds__(512, 4) void attn(const unsigned short* __restrict__ QKV,
                                               const unsigned short* __restrict__ Vg,
                                               const unsigned long long* __restrict__ Mb,
                                               unsigned short* __restrict__ O)
{
  __shared__ char smem[49152];
  unsigned short* Ks = (unsigned short*)smem;            // [3][64][64] xor-swizzled 16B blocks
  unsigned short* Vt = (unsigned short*)(smem + 24576);  // [3][64][64] [d][key] xor-swizzled

  const int tid = threadIdx.x, wave = tid >> 6, lane = tid & 63;
  const int l16 = lane & 15, quad = lane >> 4;
  const int id = blockIdx.x;
  const int xcd = id & 7, m = id >> 3;         // m in 0..63
  const int bh = xcd * 4 + (m >> 4);           // 4 bh per XCD (K/V stay in this XCD's L2)
  const int qblk = (m & 15) * 128;             // 128 q-rows per block (8 waves x 16)
  const int b = bh >> 4, h = bh & 15;
  const unsigned short* Qg  = QKV + (size_t)b * 2048 * 3072 + h * 64;
  const unsigned short* Kg  = Qg + 1024;
  const unsigned short* Vgb = Vg + (size_t)bh * 64 * 2048;

  const int qrow = qblk + wave*16 + l16;       // this lane's q (B-frag row, lsum owner)
  const unsigned long long* mrow = Mb + (size_t)b*2048 + qrow;   // + c*4096 per chunk

  // Q B-fragment: B[n=q=l16][k=d=ks*32+quad*8+j]
  short8 qf0 = *(const short8*)(Qg + (size_t)qrow * 3072 + quad*8);
  short8 qf1 = *(const short8*)(Qg + (size_t)qrow * 3072 + 32 + quad*8);

  f32x4 oacc[4] = {};               // O[q=quad*4+r][d=ng*16+l16]
  float plsum = 0.f;
  const int sw = l16 & 7;

  // per-thread staging geometry: 512 threads cover one 8KB slot in one pass
  const int srow = tid >> 3;                   // 0..63
  const int sbg  = (tid & 7) ^ (srow & 7);     // xor-swizzled 16B block

  // prologue: stage chunks 0,1 into slots 0,1; masks 0,1 (10 VMEM ops, drained at c=0)
  stage16(Kg  + (size_t)srow * 3072 + sbg * 8,        Ks + tid * 8);
  stage16(Vgb + (size_t)srow * 2048 + sbg * 8,        Vt + tid * 8);
  stage16(Kg  + (size_t)(64 + srow) * 3072 + sbg * 8, Ks + 4096 + tid * 8);
  stage16(Vgb + (size_t)srow * 2048 + 64 + sbg * 8,   Vt + 4096 + tid * 8);
  unsigned long long mcur = mrow[0];
  unsigned long long mnxt = mrow[4096];
  unsigned long long mnn  = 0ull;

  int sc = 0;                        // slot of chunk c
  for (int c = 0; c < 32; c++){
    // wait: chunk-c DMAs + mask landed (counted, order-robust); LDS reads of the
    // slot being re-targeted are done (lgkm)
    if (c == 0 || c == 31){
      __asm__ volatile("s_waitcnt vmcnt(0) lgkmcnt(0)" ::: "memory");
    } else {
      __asm__ volatile("s_waitcnt vmcnt(3) lgkmcnt(0)" ::: "memory");
    }
    __builtin_amdgcn_s_barrier();
    __builtin_amdgcn_sched_barrier(0);

    // issue chunk c+2 DMAs into slot (sc+2)%3 + mask prefetch (3 VMEM ops)
    if (c < 30){
      int s2 = sc + 2; if (s2 >= 3) s2 -= 3;
      const int nj = (c + 2) * 64;
      const int kb2 = s2 * 4096;
      stage16(Kg  + (size_t)(nj + srow) * 3072 + sbg * 8, Ks + kb2 + tid * 8);
      stage16(Vgb + (size_t)srow * 2048 + nj + sbg * 8,   Vt + kb2 + tid * 8);
      mnn = mrow[(size_t)(c + 2) * 4096];
    }

    // fully wave-private body on slot sc: 4 key-blocks; QK -> exp -> in-reg P -> PV
    const int buf = sc * 4096;
    #pragma unroll
    for (int kb = 0; kb < 4; kb++){
      const int krow = kb*16 + l16;           // A[m=key] row in Ks
      short8 kf0 = *(const short8*)&Ks[buf + krow*64 + ((0 + quad) ^ sw) * 8];
      short8 kf1 = *(const short8*)&Ks[buf + krow*64 + ((4 + quad) ^ sw) * 8];
      f32x4 a = {0.f, 0.f, 0.f, 0.f};
      a = __builtin_amdgcn_mfma_f32_16x16x32_bf16(kf0, qf0, a, 0, 0, 0);
      a = __builtin_amdgcn_mfma_f32_16x16x32_bf16(kf1, qf1, a, 0, 0, 0);
      // S^T[key=quad*4+r][q=l16]; log2 domain (log2e folded into Wq); masked -> 1.0
      unsigned mm = (unsigned)(mcur >> (kb*16 + quad*4)) & 15u;
      float p0 = EXP2(a[0]); p0 = (mm & 1u) ? p0 : 1.0f;
      float p1 = EXP2(a[1]); p1 = (mm & 2u) ? p1 : 1.0f;
      float p2 = EXP2(a[2]); p2 = (mm & 4u) ? p2 : 1.0f;
      float p3 = EXP2(a[3]); p3 = (mm & 8u) ? p3 : 1.0f;
      plsum += (p0 + p1) + (p2 + p3);
      uint2 pu; pu.x = pack_bf16_rn(p0, p1); pu.y = pack_bf16_rn(p2, p3);
      short4v pa = *(short4v*)&pu;            // A[m=q=l16][k=key=quad*4+j] == S^T regs
      #pragma unroll
      for (int ng = 0; ng < 4; ng++){
        const int vrow = ng*16 + l16;         // B[n=d] row in Vt
        short4v vf = *(const short4v*)&Vt[buf + vrow*64 +
                       ((kb*2 + (quad >> 1)) ^ sw) * 8 + (quad & 1) * 4];
        oacc[ng] = __builtin_amdgcn_mfma_f32_16x16x16bf16_1k(pa, vf, oacc[ng], 0, 0, 0);
      }
    }
    mcur = mnxt; mnxt = mnn;
    sc += 1; if (sc == 3) sc = 0;
  }

  // ---- epilogue: shfl-only lsum reduce; scale; direct store (no LDS, no sync) ----
  float v = plsum;
  v += __shfl_xor(v, 16);
  v += __shfl_xor(v, 32);
  float linv = 1.0f / v;                      // total for q = l16
  float lr[4];
  #pragma unroll
  for (int r = 0; r < 4; r++) lr[r] = __shfl(linv, quad*4 + r);   // for q = quad*4+r

  unsigned short* Ob = O + (size_t)(b*2048 + qblk + wave*16) * 1024 + h*64;
  #pragma unroll
  for (int ng = 0; ng < 4; ng++)
    #pragma unroll
    for (int r = 0; r < 4; r++)
      Ob[(size_t)(quad*4 + r) * 1024 + ng*16 + l16] = f2bf(oacc[ng][r] * lr[r]);
}

// ---------------- launch ----------------
extern "C" void kernel_launch(void* const* d_in, const int* in_sizes, int n_in,
                              void* d_out, int out_size, void* d_ws, size_t ws_size,
                              hipStream_t stream)
{
  const float* X  = (const float*)d_in[0];
  const int*   Mk = (const int*)d_in[1];
  const float* Wq = (const float*)d_in[2];
  const float* Wk = (const float*)d_in[3];
  const float* Wv = (const float*)d_in[4];
  const float* Wo = (const float*)d_in[5];
  float* out = (float*)d_out;

  char* ws = (char*)d_ws;
  unsigned short* Xb   = (unsigned short*)(ws + 0);          //  8 MB  [4096][1024]
  unsigned short* Wqkv = (unsigned short*)(ws + 8388608);    //  6 MB  [3072][1024]
  unsigned short* Wob  = (unsigned short*)(ws + 14680064);   //  2 MB  [1024][1024]
  unsigned short* QKV  = (unsigned short*)(ws + 16777216);   // 24 MB  [4096][3072] (V cols unused)
  unsigned short* Ob   = (unsigned short*)(ws + 41943040);   //  8 MB  [4096][1024]
  unsigned long long* Mb = (unsigned long long*)(ws + 50331648); // 1 MB [32 words][4096 rows]
  unsigned short* Vg   = (unsigned short*)(ws + 58720256);   //  8 MB  [32][64][2048]

  prep<<<12288, 256, 0, stream>>>(X, Mk, Wq, Wk, Wv, Wo, Xb, Wqkv, Wob, Mb);
  gemm_qkv<<<768, 256, 0, stream>>>(Xb, Wqkv, QKV, Vg);
  attn<<<512, 512, 0, stream>>>(QKV, Vg, Mb, Ob);
  gemm_out<<<512, 256, 0, stream>>>(Ob, Wob, out);
}

// Round 11
// 242.461 us; speedup vs baseline: 1.0767x; 1.0203x over previous
//
#include <hip/hip_runtime.h>
#include <hip/hip_bf16.h>

using short8  = __attribute__((ext_vector_type(8))) short;
using short4v = __attribute__((ext_vector_type(4))) short;
using f32x4   = __attribute__((ext_vector_type(4))) float;

#if __has_builtin(__builtin_amdgcn_exp2f)
#define EXP2(x) __builtin_amdgcn_exp2f(x)
#else
#define EXP2(x) __expf(0.6931471805599453f*(x))
#endif

__device__ __forceinline__ unsigned short f2bf(float x){
  union { float f; unsigned u; } c; c.f = x;
  unsigned u = c.u + 0x7FFFu + ((c.u >> 16) & 1u);
  return (unsigned short)(u >> 16);
}

__device__ __forceinline__ unsigned pack_bf16_rn(float a, float b){
  __hip_bfloat162 t = __float22bfloat162_rn(make_float2(a, b));
  unsigned u; __builtin_memcpy(&u, &t, 4);
  return u;
}

// ---------------- fused prep: dtype conversions + mask bit-pack (transposed) ----
// bid < 8192: bf16 conversions (X, Wq*log2e/8, Wk, Wv, Wo)
// bid in [8192,12288): mask -> 1 bit/key via ballot, TRANSPOSED layout:
// Mbits[word][row], word w covers keys w*64..w*64+63 of row (b*2048+q).
__global__ __launch_bounds__(256) void prep(const float* __restrict__ X, const int* __restrict__ Mk,
                                            const float* __restrict__ Wq, const float* __restrict__ Wk,
                                            const float* __restrict__ Wv, const float* __restrict__ Wo,
                                            unsigned short* __restrict__ Xb, unsigned short* __restrict__ Wqkv,
                                            unsigned short* __restrict__ Wob, unsigned long long* __restrict__ Mbits)
{
  const int bid = blockIdx.x, tid = threadIdx.x;
  if (bid < 8192){
    const float* src; unsigned short* dst; float scale; int i;
    if (bid < 4096)      { src = X;  dst = Xb;             scale = 1.0f;          i = bid*1024 + tid*4; }
    else if (bid < 5120) { src = Wq; dst = Wqkv;           scale = 0.18033688f;   i = (bid-4096)*1024 + tid*4; } // 1/8 * log2(e)
    else if (bid < 6144) { src = Wk; dst = Wqkv + 1048576; scale = 1.0f;          i = (bid-5120)*1024 + tid*4; }
    else if (bid < 7168) { src = Wv; dst = Wqkv + 2097152; scale = 1.0f;          i = (bid-6144)*1024 + tid*4; }
    else                 { src = Wo; dst = Wob;            scale = 1.0f;          i = (bid-7168)*1024 + tid*4; }
    float4 v = *(const float4*)(src + i);
    ushort4 o;
    o.x = f2bf(v.x * scale); o.y = f2bf(v.y * scale);
    o.z = f2bf(v.z * scale); o.w = f2bf(v.w * scale);
    *(ushort4*)(dst + i) = o;
  } else {
    int row = bid - 8192;                       // 0..4095 = b*2048+q
    const int* src = Mk + (size_t)row * 2048;
    int w = tid >> 6, l = tid & 63;
    #pragma unroll
    for (int p = 0; p < 8; p++){
      int v = src[w*512 + p*64 + l];            // coalesced 256B per ballot
      unsigned long long bm = __ballot(v != 0);
      if (l == 0) Mbits[(size_t)(w*8 + p) * 4096 + row] = bm;  // [word][row]
    }
  }
}

// ---------------- async global->LDS, width 16 ----------------
__device__ __forceinline__ void stage16(const unsigned short* g, unsigned short* l){
  __builtin_amdgcn_global_load_lds(
      (const __attribute__((address_space(1))) void*)g,
      (__attribute__((address_space(3))) void*)l, 16, 0, 0);
}

// ---------------- gemm1: QKV = Xb * Wqkv^T; V-blocks write Vg transposed ----------
__global__ __launch_bounds__(256) void gemm_qkv(const unsigned short* __restrict__ A,
                                                const unsigned short* __restrict__ B,
                                                unsigned short* __restrict__ C,
                                                unsigned short* __restrict__ Vg)
{
  __shared__ unsigned short As[128*32];
  __shared__ unsigned short Bs[128*32];
  const int tid = threadIdx.x;
  const int wave = tid >> 6, lane = tid & 63, l16 = lane & 15, quad = lane >> 4;
  const int id = blockIdx.x, xcd = id & 7, m = id >> 3;
  const int bm = (m / 3) * 128, bn = (xcd * 3 + (m % 3)) * 128;
  const int wm = (wave >> 1) * 64, wn = (wave & 1) * 64;
  const int K = 1024;

  f32x4 acc[4][4] = {};
  for (int k0 = 0; k0 < K; k0 += 32){
    #pragma unroll
    for (int c = 0; c < 2; c++){
      int idx = c * 256 + tid;
      int row = idx >> 2, g = (idx & 3) * 8;
      stage16(A + (size_t)(bm + row) * K + k0 + g, &As[idx * 8]);
      stage16(B + (size_t)(bn + row) * K + k0 + g, &Bs[idx * 8]);
    }
    __syncthreads();
    short8 af[4], bf[4];
    #pragma unroll
    for (int i = 0; i < 4; i++) af[i] = *(const short8*)&As[(wm + i*16 + l16)*32 + quad*8];
    #pragma unroll
    for (int j = 0; j < 4; j++) bf[j] = *(const short8*)&Bs[(wn + j*16 + l16)*32 + quad*8];
    #pragma unroll
    for (int i = 0; i < 4; i++)
      #pragma unroll
      for (int j = 0; j < 4; j++)
        acc[i][j] = __builtin_amdgcn_mfma_f32_16x16x32_bf16(af[i], bf[j], acc[i][j], 0, 0, 0);
    __syncthreads();
  }

  if (bn < 2048){
    #pragma unroll
    for (int i = 0; i < 4; i++){
      int mrow = bm + wm + i*16 + quad*4;
      #pragma unroll
      for (int j = 0; j < 4; j++){
        int ncol = bn + wn + j*16 + l16;
        #pragma unroll
        for (int r = 0; r < 4; r++)
          C[(size_t)(mrow + r) * 3072 + ncol] = f2bf(acc[i][j][r]);
      }
    }
  } else {
    #pragma unroll
    for (int i = 0; i < 4; i++){
      int srow = bm + wm + i*16 + quad*4;
      int b = srow >> 11, s = srow & 2047;
      #pragma unroll
      for (int j = 0; j < 4; j++){
        int c = bn - 2048 + wn + j*16 + l16;
        int h = c >> 6, d = c & 63;
        ushort4 o;
        o.x = f2bf(acc[i][j][0]); o.y = f2bf(acc[i][j][1]);
        o.z = f2bf(acc[i][j][2]); o.w = f2bf(acc[i][j][3]);
        *(ushort4*)&Vg[((size_t)(b*16 + h)*64 + d) * 2048 + s] = o;
      }
    }
  }
}

// ---------------- gemm2: out = Ob * Wob^T (f32 out), 128x64 tiles, XCD-swizzled ----
__global__ __launch_bounds__(256) void gemm_out(const unsigned short* __restrict__ A,
                                                const unsigned short* __restrict__ B,
                                                float* __restrict__ Cf)
{
  __shared__ unsigned short As[128*32];
  __shared__ unsigned short Bs[64*32];
  const int tid = threadIdx.x;
  const int wave = tid >> 6, lane = tid & 63, l16 = lane & 15, quad = lane >> 4;
  const int id = blockIdx.x, xcd = id & 7, m = id >> 3;
  const int bm = (m >> 1) * 128, bn = (xcd * 2 + (m & 1)) * 64;
  const int wm = (wave >> 1) * 64, wn = (wave & 1) * 32;
  const int K = 1024, N = 1024;

  f32x4 acc[4][2] = {};
  for (int k0 = 0; k0 < K; k0 += 32){
    #pragma unroll
    for (int c = 0; c < 2; c++){
      int idx = c * 256 + tid;
      int row = idx >> 2, g = (idx & 3) * 8;
      stage16(A + (size_t)(bm + row) * K + k0 + g, &As[idx * 8]);
    }
    stage16(B + (size_t)(bn + (tid >> 2)) * K + k0 + (tid & 3) * 8, &Bs[tid * 8]);
    __syncthreads();
    short8 af[4], bf[2];
    #pragma unroll
    for (int i = 0; i < 4; i++) af[i] = *(const short8*)&As[(wm + i*16 + l16)*32 + quad*8];
    #pragma unroll
    for (int j = 0; j < 2; j++) bf[j] = *(const short8*)&Bs[(wn + j*16 + l16)*32 + quad*8];
    #pragma unroll
    for (int i = 0; i < 4; i++)
      #pragma unroll
      for (int j = 0; j < 2; j++)
        acc[i][j] = __builtin_amdgcn_mfma_f32_16x16x32_bf16(af[i], bf[j], acc[i][j], 0, 0, 0);
    __syncthreads();
  }
  #pragma unroll
  for (int i = 0; i < 4; i++){
    int mrow = bm + wm + i*16 + quad*4;
    #pragma unroll
    for (int j = 0; j < 2; j++){
      int ncol = bn + wn + j*16 + l16;
      #pragma unroll
      for (int r = 0; r < 4; r++)
        Cf[(size_t)(mrow + r) * N + ncol] = acc[i][j][r];
    }
  }
}

// ---------------- attention: wave-autonomous split-K, 32 waves/CU ---------------
// Rounds 7/10: wave-autonomous kernel is ISSUE-BOUND (VALU 57-63%, MFMA 27-29%);
// counted-vmcnt ring neutral; wall ~ fixed VALU work / fed-rate. The decomposition
// capped occupancy at 16 waves/CU (65536 q-rows / 16 per wave / 256 CU). Fix:
// SPLIT-K. Block = 8 waves / 64 q-rows; waves 0-3 process keys 0..1023, waves
// 4-7 keys 1024..2047 (no max-tracking softmax -> partials add). 32-key chunks,
// two double-buffered K/V streams = 32KB LDS -> grid 1024 = 4 blocks/CU = 32
// waves/CU (8/SIMD feeds the issue port). launch_bounds(512,8) caps VGPR at 64
// (round 10: 48). Sync = proven round-7 per-chunk __syncthreads. Mask words now
// u32 (cheaper shifts). V swizzle at 16B granularity via pre-swizzled global
// source (2-way bank alias = free). Epilogue: partner waves combine O/lsum via
// dead LDS buffers.
__global__ __launch_bounds__(512, 8) void attn(const unsigned short* __restrict__ QKV,
                                               const unsigned short* __restrict__ Vg,
                                               const unsigned long long* __restrict__ Mb,
                                               unsigned short* __restrict__ O)
{
  __shared__ char smem[32768];
  unsigned short* Ks = (unsigned short*)smem;            // [2 str][2 buf][32 key][64 d] 16KB
  unsigned short* Vt = (unsigned short*)(smem + 16384);  // [2 str][2 buf][64 d][32 key] 16KB

  const int tid = threadIdx.x, wave = tid >> 6, lane = tid & 63;
  const int l16 = lane & 15, quad = lane >> 4;
  const int st = tid >> 8;                     // key-stream: waves 0-3 -> 0, 4-7 -> 1
  const int wlocal = wave & 3;                 // q-group within block
  const int id = blockIdx.x;
  const int xcd = id & 7, m = id >> 3;         // m in 0..127
  const int bh = xcd * 4 + (m >> 5);           // 4 bh per XCD (K/V stay in this XCD's L2)
  const int qblk = (m & 31) * 64;              // 64 q-rows per block
  const int b = bh >> 4, h = bh & 15;
  const unsigned short* Qg  = QKV + (size_t)b * 2048 * 3072 + h * 64;
  const unsigned short* Kg  = Qg + 1024;
  const unsigned short* Vgb = Vg + (size_t)bh * 64 * 2048;
  const unsigned* Mb32 = (const unsigned*)Mb;

  const int qrow = qblk + wlocal*16 + l16;     // this lane's q
  const int mrowi = (b*2048 + qrow) * 2;       // u32 base index into Mbits[word][row]

  // Q B-fragment: B[n=q=l16][k=d=ks*32+quad*8+j]
  short8 qf0 = *(const short8*)(Qg + (size_t)qrow * 3072 + quad*8);
  short8 qf1 = *(const short8*)(Qg + (size_t)qrow * 3072 + 32 + quad*8);

  f32x4 oacc[4] = {};               // O[q=quad*4+r][d=ng*16+l16] (partial: this stream's keys)
  float plsum = 0.f;
  const int sw = l16 & 7;

  // staging geometry: t in [0,256) per stream; K: 32 rows x 128B; V: 64 rows x 64B
  const int t = tid & 255;
  const int rowK = t >> 3, bgK = (t & 7) ^ (rowK & 7);          // 16B-block xor-swizzle
  const int rowV = t >> 2, bgV = (t & 3) ^ ((rowV >> 1) & 3);   // 16B-block xor-swizzle
  const int kbase = st * 1024;                 // this stream's key offset

  // prologue: stage chunk 0 of this thread's stream into buffer 0; mask word 0
  stage16(Kg  + (size_t)(kbase + rowK) * 3072 + bgK * 8,   Ks + (st*2 + 0) * 2048 + t * 8);
  stage16(Vgb + (size_t)rowV * 2048 + kbase + bgV * 8,     Vt + (st*2 + 0) * 2048 + t * 8);
  unsigned mcur = Mb32[(size_t)(st*16) * 8192 + mrowi];
  unsigned mnxt = 0u;

  for (int c = 0; c < 32; c++){
    __syncthreads();   // chunk-c DMAs landed (vmcnt); all waves done reading buf^1

    // issue chunk c+1 DMAs into the other buffer + mask prefetch
    if (c < 31){
      const int cj = c + 1, so = (st*2 + (cj & 1)) * 2048;
      const int kj = kbase + cj * 32;
      stage16(Kg  + (size_t)(kj + rowK) * 3072 + bgK * 8, Ks + so + t * 8);
      stage16(Vgb + (size_t)rowV * 2048 + kj + bgV * 8,   Vt + so + t * 8);
      mnxt = Mb32[(size_t)(st*16 + (cj >> 1)) * 8192 + mrowi + (cj & 1)];
    }

    // wave-private body on this stream's current buffer: 2 key-blocks of 16
    const int bufo = (st*2 + (c & 1)) * 2048;
    #pragma unroll
    for (int kb = 0; kb < 2; kb++){
      const int krow = kb*16 + l16;           // A[m=key] row in Ks
      short8 kf0 = *(const short8*)&Ks[bufo + krow*64 + ((0 + quad) ^ sw) * 8];
      short8 kf1 = *(const short8*)&Ks[bufo + krow*64 + ((4 + quad) ^ sw) * 8];
      f32x4 a = {0.f, 0.f, 0.f, 0.f};
      a = __builtin_amdgcn_mfma_f32_16x16x32_bf16(kf0, qf0, a, 0, 0, 0);
      a = __builtin_amdgcn_mfma_f32_16x16x32_bf16(kf1, qf1, a, 0, 0, 0);
      // S^T[key=quad*4+r][q=l16]; log2 domain (log2e folded into Wq); masked -> 1.0
      unsigned mm = (mcur >> (kb*16 + quad*4)) & 15u;
      float p0 = EXP2(a[0]); p0 = (mm & 1u) ? p0 : 1.0f;
      float p1 = EXP2(a[1]); p1 = (mm & 2u) ? p1 : 1.0f;
      float p2 = EXP2(a[2]); p2 = (mm & 4u) ? p2 : 1.0f;
      float p3 = EXP2(a[3]); p3 = (mm & 8u) ? p3 : 1.0f;
      plsum += (p0 + p1) + (p2 + p3);
      uint2 pu; pu.x = pack_bf16_rn(p0, p1); pu.y = pack_bf16_rn(p2, p3);
      short4v pa = *(short4v*)&pu;            // A[m=q=l16][k=key=quad*4+j] == S^T regs
      #pragma unroll
      for (int ng = 0; ng < 4; ng++){
        const int vrow = ng*16 + l16;         // B[n=d] row in Vt
        const int phys8 = (kb*2 + (quad >> 1)) ^ ((vrow >> 1) & 3);
        short4v vf = *(const short4v*)&Vt[bufo + vrow*32 + phys8*8 + (quad & 1) * 4];
        oacc[ng] = __builtin_amdgcn_mfma_f32_16x16x16bf16_1k(pa, vf, oacc[ng], 0, 0, 0);
      }
    }
    mcur = mnxt;
  }

  // ---- epilogue: combine the two key-streams via dead LDS; store (stream 0 only) ----
  float* fb = (float*)smem;
  __syncthreads();                  // all body LDS reads done; buffers dead
  if (st == 1){
    const int o = (wlocal*64 + lane) * 17;
    #pragma unroll
    for (int ng = 0; ng < 4; ng++)
      #pragma unroll
      for (int r = 0; r < 4; r++) fb[o + ng*4 + r] = oacc[ng][r];
    fb[o + 16] = plsum;
  }
  __syncthreads();
  if (st == 0){
    const int o = (wlocal*64 + lane) * 17;
    #pragma unroll
    for (int ng = 0; ng < 4; ng++)
      #pragma unroll
      for (int r = 0; r < 4; r++) oacc[ng][r] += fb[o + ng*4 + r];
    plsum += fb[o + 16];

    float v = plsum;
    v += __shfl_xor(v, 16);
    v += __shfl_xor(v, 32);
    float linv = 1.0f / v;                    // total for q = l16
    float lr[4];
    #pragma unroll
    for (int r = 0; r < 4; r++) lr[r] = __shfl(linv, quad*4 + r);   // for q = quad*4+r

    unsigned short* Ob = O + (size_t)(b*2048 + qblk + wlocal*16) * 1024 + h*64;
    #pragma unroll
    for (int ng = 0; ng < 4; ng++)
      #pragma unroll
      for (int r = 0; r < 4; r++)
        Ob[(size_t)(quad*4 + r) * 1024 + ng*16 + l16] = f2bf(oacc[ng][r] * lr[r]);
  }
}

// ---------------- launch ----------------
extern "C" void kernel_launch(void* const* d_in, const int* in_sizes, int n_in,
                              void* d_out, int out_size, void* d_ws, size_t ws_size,
                              hipStream_t stream)
{
  const float* X  = (const float*)d_in[0];
  const int*   Mk = (const int*)d_in[1];
  const float* Wq = (const float*)d_in[2];
  const float* Wk = (const float*)d_in[3];
  const float* Wv = (const float*)d_in[4];
  const float* Wo = (const float*)d_in[5];
  float* out = (float*)d_out;

  char* ws = (char*)d_ws;
  unsigned short* Xb   = (unsigned short*)(ws + 0);          //  8 MB  [4096][1024]
  unsigned short* Wqkv = (unsigned short*)(ws + 8388608);    //  6 MB  [3072][1024]
  unsigned short* Wob  = (unsigned short*)(ws + 14680064);   //  2 MB  [1024][1024]
  unsigned short* QKV  = (unsigned short*)(ws + 16777216);   // 24 MB  [4096][3072] (V cols unused)
  unsigned short* Ob   = (unsigned short*)(ws + 41943040);   //  8 MB  [4096][1024]
  unsigned long long* Mb = (unsigned long long*)(ws + 50331648); // 1 MB [32 words][4096 rows]
  unsigned short* Vg   = (unsigned short*)(ws + 58720256);   //  8 MB  [32][64][2048]

  prep<<<12288, 256, 0, stream>>>(X, Mk, Wq, Wk, Wv, Wo, Xb, Wqkv, Wob, Mb);
  gemm_qkv<<<768, 256, 0, stream>>>(Xb, Wqkv, QKV, Vg);
  attn<<<1024, 512, 0, stream>>>(QKV, Vg, Mb, Ob);
  gemm_out<<<512, 256, 0, stream>>>(Ob, Wob, out);
}

// Round 12
// 240.686 us; speedup vs baseline: 1.0847x; 1.0074x over previous
//
#include <hip/hip_runtime.h>
#include <hip/hip_bf16.h>

using short8  = __attribute__((ext_vector_type(8))) short;
using short4v = __attribute__((ext_vector_type(4))) short;
using f32x4   = __attribute__((ext_vector_type(4))) float;

#if __has_builtin(__builtin_amdgcn_exp2f)
#define EXP2(x) __builtin_amdgcn_exp2f(x)
#else
#define EXP2(x) __expf(0.6931471805599453f*(x))
#endif

__device__ __forceinline__ unsigned short f2bf(float x){
  union { float f; unsigned u; } c; c.f = x;
  unsigned u = c.u + 0x7FFFu + ((c.u >> 16) & 1u);
  return (unsigned short)(u >> 16);
}

__device__ __forceinline__ unsigned pack_bf16_rn(float a, float b){
  __hip_bfloat162 t = __float22bfloat162_rn(make_float2(a, b));
  unsigned u; __builtin_memcpy(&u, &t, 4);
  return u;
}

// ---------------- fused prep: dtype conversions + mask bit-pack (transposed) ----
// bid < 8192: bf16 conversions (X, Wq*log2e/8, Wk, Wv, Wo)
// bid in [8192,12288): mask -> 1 bit/key via ballot, TRANSPOSED layout:
// Mbits[word][row], word w covers keys w*64..w*64+63 of row (b*2048+q).
__global__ __launch_bounds__(256) void prep(const float* __restrict__ X, const int* __restrict__ Mk,
                                            const float* __restrict__ Wq, const float* __restrict__ Wk,
                                            const float* __restrict__ Wv, const float* __restrict__ Wo,
                                            unsigned short* __restrict__ Xb, unsigned short* __restrict__ Wqkv,
                                            unsigned short* __restrict__ Wob, unsigned long long* __restrict__ Mbits)
{
  const int bid = blockIdx.x, tid = threadIdx.x;
  if (bid < 8192){
    const float* src; unsigned short* dst; float scale; int i;
    if (bid < 4096)      { src = X;  dst = Xb;             scale = 1.0f;          i = bid*1024 + tid*4; }
    else if (bid < 5120) { src = Wq; dst = Wqkv;           scale = 0.18033688f;   i = (bid-4096)*1024 + tid*4; } // 1/8 * log2(e)
    else if (bid < 6144) { src = Wk; dst = Wqkv + 1048576; scale = 1.0f;          i = (bid-5120)*1024 + tid*4; }
    else if (bid < 7168) { src = Wv; dst = Wqkv + 2097152; scale = 1.0f;          i = (bid-6144)*1024 + tid*4; }
    else                 { src = Wo; dst = Wob;            scale = 1.0f;          i = (bid-7168)*1024 + tid*4; }
    float4 v = *(const float4*)(src + i);
    ushort4 o;
    o.x = f2bf(v.x * scale); o.y = f2bf(v.y * scale);
    o.z = f2bf(v.z * scale); o.w = f2bf(v.w * scale);
    *(ushort4*)(dst + i) = o;
  } else {
    int row = bid - 8192;                       // 0..4095 = b*2048+q
    const int* src = Mk + (size_t)row * 2048;
    int w = tid >> 6, l = tid & 63;
    #pragma unroll
    for (int p = 0; p < 8; p++){
      int v = src[w*512 + p*64 + l];            // coalesced 256B per ballot
      unsigned long long bm = __ballot(v != 0);
      if (l == 0) Mbits[(size_t)(w*8 + p) * 4096 + row] = bm;  // [word][row]
    }
  }
}

// ---------------- async global->LDS, width 16 ----------------
__device__ __forceinline__ void stage16(const unsigned short* g, unsigned short* l){
  __builtin_amdgcn_global_load_lds(
      (const __attribute__((address_space(1))) void*)g,
      (__attribute__((address_space(3))) void*)l, 16, 0, 0);
}

// ---------------- gemm1: QKV = Xb * Wqkv^T; V-blocks write Vg transposed ----------
__global__ __launch_bounds__(256) void gemm_qkv(const unsigned short* __restrict__ A,
                                                const unsigned short* __restrict__ B,
                                                unsigned short* __restrict__ C,
                                                unsigned short* __restrict__ Vg)
{
  __shared__ unsigned short As[128*32];
  __shared__ unsigned short Bs[128*32];
  const int tid = threadIdx.x;
  const int wave = tid >> 6, lane = tid & 63, l16 = lane & 15, quad = lane >> 4;
  const int id = blockIdx.x, xcd = id & 7, m = id >> 3;
  const int bm = (m / 3) * 128, bn = (xcd * 3 + (m % 3)) * 128;
  const int wm = (wave >> 1) * 64, wn = (wave & 1) * 64;
  const int K = 1024;

  f32x4 acc[4][4] = {};
  for (int k0 = 0; k0 < K; k0 += 32){
    #pragma unroll
    for (int c = 0; c < 2; c++){
      int idx = c * 256 + tid;
      int row = idx >> 2, g = (idx & 3) * 8;
      stage16(A + (size_t)(bm + row) * K + k0 + g, &As[idx * 8]);
      stage16(B + (size_t)(bn + row) * K + k0 + g, &Bs[idx * 8]);
    }
    __syncthreads();
    short8 af[4], bf[4];
    #pragma unroll
    for (int i = 0; i < 4; i++) af[i] = *(const short8*)&As[(wm + i*16 + l16)*32 + quad*8];
    #pragma unroll
    for (int j = 0; j < 4; j++) bf[j] = *(const short8*)&Bs[(wn + j*16 + l16)*32 + quad*8];
    #pragma unroll
    for (int i = 0; i < 4; i++)
      #pragma unroll
      for (int j = 0; j < 4; j++)
        acc[i][j] = __builtin_amdgcn_mfma_f32_16x16x32_bf16(af[i], bf[j], acc[i][j], 0, 0, 0);
    __syncthreads();
  }

  if (bn < 2048){
    #pragma unroll
    for (int i = 0; i < 4; i++){
      int mrow = bm + wm + i*16 + quad*4;
      #pragma unroll
      for (int j = 0; j < 4; j++){
        int ncol = bn + wn + j*16 + l16;
        #pragma unroll
        for (int r = 0; r < 4; r++)
          C[(size_t)(mrow + r) * 3072 + ncol] = f2bf(acc[i][j][r]);
      }
    }
  } else {
    #pragma unroll
    for (int i = 0; i < 4; i++){
      int srow = bm + wm + i*16 + quad*4;
      int b = srow >> 11, s = srow & 2047;
      #pragma unroll
      for (int j = 0; j < 4; j++){
        int c = bn - 2048 + wn + j*16 + l16;
        int h = c >> 6, d = c & 63;
        ushort4 o;
        o.x = f2bf(acc[i][j][0]); o.y = f2bf(acc[i][j][1]);
        o.z = f2bf(acc[i][j][2]); o.w = f2bf(acc[i][j][3]);
        *(ushort4*)&Vg[((size_t)(b*16 + h)*64 + d) * 2048 + s] = o;
      }
    }
  }
}

// ---------------- gemm2: out = Ob * Wob^T (f32 out), 128x64 tiles, XCD-swizzled ----
__global__ __launch_bounds__(256) void gemm_out(const unsigned short* __restrict__ A,
                                                const unsigned short* __restrict__ B,
                                                float* __restrict__ Cf)
{
  __shared__ unsigned short As[128*32];
  __shared__ unsigned short Bs[64*32];
  const int tid = threadIdx.x;
  const int wave = tid >> 6, lane = tid & 63, l16 = lane & 15, quad = lane >> 4;
  const int id = blockIdx.x, xcd = id & 7, m = id >> 3;
  const int bm = (m >> 1) * 128, bn = (xcd * 2 + (m & 1)) * 64;
  const int wm = (wave >> 1) * 64, wn = (wave & 1) * 32;
  const int K = 1024, N = 1024;

  f32x4 acc[4][2] = {};
  for (int k0 = 0; k0 < K; k0 += 32){
    #pragma unroll
    for (int c = 0; c < 2; c++){
      int idx = c * 256 + tid;
      int row = idx >> 2, g = (idx & 3) * 8;
      stage16(A + (size_t)(bm + row) * K + k0 + g, &As[idx * 8]);
    }
    stage16(B + (size_t)(bn + (tid >> 2)) * K + k0 + (tid & 3) * 8, &Bs[tid * 8]);
    __syncthreads();
    short8 af[4], bf[2];
    #pragma unroll
    for (int i = 0; i < 4; i++) af[i] = *(const short8*)&As[(wm + i*16 + l16)*32 + quad*8];
    #pragma unroll
    for (int j = 0; j < 2; j++) bf[j] = *(const short8*)&Bs[(wn + j*16 + l16)*32 + quad*8];
    #pragma unroll
    for (int i = 0; i < 4; i++)
      #pragma unroll
      for (int j = 0; j < 2; j++)
        acc[i][j] = __builtin_amdgcn_mfma_f32_16x16x32_bf16(af[i], bf[j], acc[i][j], 0, 0, 0);
    __syncthreads();
  }
  #pragma unroll
  for (int i = 0; i < 4; i++){
    int mrow = bm + wm + i*16 + quad*4;
    #pragma unroll
    for (int j = 0; j < 2; j++){
      int ncol = bn + wn + j*16 + l16;
      #pragma unroll
      for (int r = 0; r < 4; r++)
        Cf[(size_t)(mrow + r) * N + ncol] = acc[i][j][r];
    }
  }
}

// ---------------- attention: wave-autonomous split-K, 32 waves/CU, no spills ----
// Round 11 (split-K, launch_bounds(512,8)): occupancy 36->59% but dur flat 76us.
// Counters exposed why: VGPR forced to 32 (below the live set) -> scratch spills
// (WRITE_SIZE 8192->14336 KB, +6MB/dispatch of spill traffic). The occupancy
// experiment never ran clean. Fix: launch_bounds(512,4) -> VGPR cap 128, compiler
// lands ~48 (round 10 compiled this body at 48), which is <=64 so the HW still
// fits 4 blocks/CU = 32 waves/CU (LDS 4x32KB=128KB). Same split-K structure:
// 8 waves / 64 q-rows per block; waves 0-3 keys 0..1023, waves 4-7 keys
// 1024..2047 (no-max softmax -> partials add); 32-key chunks, double-buffered
// per stream; per-chunk __syncthreads (round-7 proven); epilogue combines the
// two streams via dead LDS.
__global__ __launch_bounds__(512, 4) void attn(const unsigned short* __restrict__ QKV,
                                               const unsigned short* __restrict__ Vg,
                                               const unsigned long long* __restrict__ Mb,
                                               unsigned short* __restrict__ O)
{
  __shared__ char smem[32768];
  unsigned short* Ks = (unsigned short*)smem;            // [2 str][2 buf][32 key][64 d] 16KB
  unsigned short* Vt = (unsigned short*)(smem + 16384);  // [2 str][2 buf][64 d][32 key] 16KB

  const int tid = threadIdx.x, wave = tid >> 6, lane = tid & 63;
  const int l16 = lane & 15, quad = lane >> 4;
  const int st = tid >> 8;                     // key-stream: waves 0-3 -> 0, 4-7 -> 1
  const int wlocal = wave & 3;                 // q-group within block
  const int id = blockIdx.x;
  const int xcd = id & 7, m = id >> 3;         // m in 0..127
  const int bh = xcd * 4 + (m >> 5);           // 4 bh per XCD (K/V stay in this XCD's L2)
  const int qblk = (m & 31) * 64;              // 64 q-rows per block
  const int b = bh >> 4, h = bh & 15;
  const unsigned short* Qg  = QKV + (size_t)b * 2048 * 3072 + h * 64;
  const unsigned short* Kg  = Qg + 1024;
  const unsigned short* Vgb = Vg + (size_t)bh * 64 * 2048;
  const unsigned* Mb32 = (const unsigned*)Mb;

  const int qrow = qblk + wlocal*16 + l16;     // this lane's q
  const int mrowi = (b*2048 + qrow) * 2;       // u32 base index into Mbits[word][row]

  // Q B-fragment: B[n=q=l16][k=d=ks*32+quad*8+j]
  short8 qf0 = *(const short8*)(Qg + (size_t)qrow * 3072 + quad*8);
  short8 qf1 = *(const short8*)(Qg + (size_t)qrow * 3072 + 32 + quad*8);

  f32x4 oacc[4] = {};               // O[q=quad*4+r][d=ng*16+l16] (partial: this stream's keys)
  float plsum = 0.f;
  const int sw = l16 & 7;

  // staging geometry: t in [0,256) per stream; K: 32 rows x 128B; V: 64 rows x 64B
  const int t = tid & 255;
  const int rowK = t >> 3, bgK = (t & 7) ^ (rowK & 7);          // 16B-block xor-swizzle
  const int rowV = t >> 2, bgV = (t & 3) ^ ((rowV >> 1) & 3);   // 16B-block xor-swizzle
  const int kbase = st * 1024;                 // this stream's key offset

  // prologue: stage chunk 0 of this thread's stream into buffer 0; mask word 0
  stage16(Kg  + (size_t)(kbase + rowK) * 3072 + bgK * 8,   Ks + (st*2 + 0) * 2048 + t * 8);
  stage16(Vgb + (size_t)rowV * 2048 + kbase + bgV * 8,     Vt + (st*2 + 0) * 2048 + t * 8);
  unsigned mcur = Mb32[(size_t)(st*16) * 8192 + mrowi];
  unsigned mnxt = 0u;

  for (int c = 0; c < 32; c++){
    __syncthreads();   // chunk-c DMAs landed (vmcnt); all waves done reading buf^1

    // issue chunk c+1 DMAs into the other buffer + mask prefetch
    if (c < 31){
      const int cj = c + 1, so = (st*2 + (cj & 1)) * 2048;
      const int kj = kbase + cj * 32;
      stage16(Kg  + (size_t)(kj + rowK) * 3072 + bgK * 8, Ks + so + t * 8);
      stage16(Vgb + (size_t)rowV * 2048 + kj + bgV * 8,   Vt + so + t * 8);
      mnxt = Mb32[(size_t)(st*16 + (cj >> 1)) * 8192 + mrowi + (cj & 1)];
    }

    // wave-private body on this stream's current buffer: 2 key-blocks of 16
    const int bufo = (st*2 + (c & 1)) * 2048;
    #pragma unroll
    for (int kb = 0; kb < 2; kb++){
      const int krow = kb*16 + l16;           // A[m=key] row in Ks
      short8 kf0 = *(const short8*)&Ks[bufo + krow*64 + ((0 + quad) ^ sw) * 8];
      short8 kf1 = *(const short8*)&Ks[bufo + krow*64 + ((4 + quad) ^ sw) * 8];
      f32x4 a = {0.f, 0.f, 0.f, 0.f};
      a = __builtin_amdgcn_mfma_f32_16x16x32_bf16(kf0, qf0, a, 0, 0, 0);
      a = __builtin_amdgcn_mfma_f32_16x16x32_bf16(kf1, qf1, a, 0, 0, 0);
      // S^T[key=quad*4+r][q=l16]; log2 domain (log2e folded into Wq); masked -> 1.0
      unsigned mm = (mcur >> (kb*16 + quad*4)) & 15u;
      float p0 = EXP2(a[0]); p0 = (mm & 1u) ? p0 : 1.0f;
      float p1 = EXP2(a[1]); p1 = (mm & 2u) ? p1 : 1.0f;
      float p2 = EXP2(a[2]); p2 = (mm & 4u) ? p2 : 1.0f;
      float p3 = EXP2(a[3]); p3 = (mm & 8u) ? p3 : 1.0f;
      plsum += (p0 + p1) + (p2 + p3);
      uint2 pu; pu.x = pack_bf16_rn(p0, p1); pu.y = pack_bf16_rn(p2, p3);
      short4v pa = *(short4v*)&pu;            // A[m=q=l16][k=key=quad*4+j] == S^T regs
      #pragma unroll
      for (int ng = 0; ng < 4; ng++){
        const int vrow = ng*16 + l16;         // B[n=d] row in Vt
        const int phys8 = (kb*2 + (quad >> 1)) ^ ((vrow >> 1) & 3);
        short4v vf = *(const short4v*)&Vt[bufo + vrow*32 + phys8*8 + (quad & 1) * 4];
        oacc[ng] = __builtin_amdgcn_mfma_f32_16x16x16bf16_1k(pa, vf, oacc[ng], 0, 0, 0);
      }
    }
    mcur = mnxt;
  }

  // ---- epilogue: combine the two key-streams via dead LDS; store (stream 0 only) ----
  float* fb = (float*)smem;
  __syncthreads();                  // all body LDS reads done; buffers dead
  if (st == 1){
    const int o = (wlocal*64 + lane) * 17;
    #pragma unroll
    for (int ng = 0; ng < 4; ng++)
      #pragma unroll
      for (int r = 0; r < 4; r++) fb[o + ng*4 + r] = oacc[ng][r];
    fb[o + 16] = plsum;
  }
  __syncthreads();
  if (st == 0){
    const int o = (wlocal*64 + lane) * 17;
    #pragma unroll
    for (int ng = 0; ng < 4; ng++)
      #pragma unroll
      for (int r = 0; r < 4; r++) oacc[ng][r] += fb[o + ng*4 + r];
    plsum += fb[o + 16];

    float v = plsum;
    v += __shfl_xor(v, 16);
    v += __shfl_xor(v, 32);
    float linv = 1.0f / v;                    // total for q = l16
    float lr[4];
    #pragma unroll
    for (int r = 0; r < 4; r++) lr[r] = __shfl(linv, quad*4 + r);   // for q = quad*4+r

    unsigned short* Ob = O + (size_t)(b*2048 + qblk + wlocal*16) * 1024 + h*64;
    #pragma unroll
    for (int ng = 0; ng < 4; ng++)
      #pragma unroll
      for (int r = 0; r < 4; r++)
        Ob[(size_t)(quad*4 + r) * 1024 + ng*16 + l16] = f2bf(oacc[ng][r] * lr[r]);
  }
}

// ---------------- launch ----------------
extern "C" void kernel_launch(void* const* d_in, const int* in_sizes, int n_in,
                              void* d_out, int out_size, void* d_ws, size_t ws_size,
                              hipStream_t stream)
{
  const float* X  = (const float*)d_in[0];
  const int*   Mk = (const int*)d_in[1];
  const float* Wq = (const float*)d_in[2];
  const float* Wk = (const float*)d_in[3];
  const float* Wv = (const float*)d_in[4];
  const float* Wo = (const float*)d_in[5];
  float* out = (float*)d_out;

  char* ws = (char*)d_ws;
  unsigned short* Xb   = (unsigned short*)(ws + 0);          //  8 MB  [4096][1024]
  unsigned short* Wqkv = (unsigned short*)(ws + 8388608);    //  6 MB  [3072][1024]
  unsigned short* Wob  = (unsigned short*)(ws + 14680064);   //  2 MB  [1024][1024]
  unsigned short* QKV  = (unsigned short*)(ws + 16777216);   // 24 MB  [4096][3072] (V cols unused)
  unsigned short* Ob   = (unsigned short*)(ws + 41943040);   //  8 MB  [4096][1024]
  unsigned long long* Mb = (unsigned long long*)(ws + 50331648); // 1 MB [32 words][4096 rows]
  unsigned short* Vg   = (unsigned short*)(ws + 58720256);   //  8 MB  [32][64][2048]

  prep<<<12288, 256, 0, stream>>>(X, Mk, Wq, Wk, Wv, Wo, Xb, Wqkv, Wob, Mb);
  gemm_qkv<<<768, 256, 0, stream>>>(Xb, Wqkv, QKV, Vg);
  attn<<<1024, 512, 0, stream>>>(QKV, Vg, Mb, Ob);
  gemm_out<<<512, 256, 0, stream>>>(Ob, Wob, out);
}